// Round 2
// baseline (611.926 us; speedup 1.0000x reference)
//
#include <hip/hip_runtime.h>

typedef short s8v __attribute__((ext_vector_type(8)));
typedef float f32x4 __attribute__((ext_vector_type(4)));

#define BM 64
#define KC 64
#define PAD 72   // LDS k-stride (bf16 elems): 144B rows, 16B-aligned, breaks pow2 banks

// LDS-only barrier: waits ds ops, does NOT drain vmcnt -> global prefetch
// loads stay in flight across the barrier (CK block_sync_lds idiom).
#define LDS_BARRIER() asm volatile("s_waitcnt lgkmcnt(0)\n\ts_barrier" ::: "memory")

__device__ __forceinline__ unsigned short f2bf(float x) {
    unsigned int u = __float_as_uint(x);
    u += 0x7fffu + ((u >> 16) & 1u);   // RNE
    return (unsigned short)(u >> 16);
}

// C[m][f] = sum_k A[m][k] * B[k][f]
// A fp32 row-major [M][lda]; Bt bf16 transposed [128 f][ldb k].
// Split-K via blockIdx.y (klen per slab); partial fp32 slab out.
// Pipeline: register-prefetch depth 2, double LDS buffer, LDS-only barriers.
__global__ __launch_bounds__(256, 2) void gemm_kernel(
    const float* __restrict__ A, int lda,
    const unsigned short* __restrict__ Bt, int ldb,
    float* __restrict__ C, int klen)
{
    __shared__ __align__(16) unsigned short As[2][BM * PAD];    // 18 KB
    __shared__ __align__(16) unsigned short Bs[2][128 * PAD];   // 36 KB -> 55KB total, 2 blocks/CU

    const int t    = threadIdx.x;
    const int w    = t >> 6;
    const int lane = t & 63;
    const int quad = lane >> 4;
    const int l16  = lane & 15;
    const int w32  = w * 32;
    const int kq   = quad * 8;

    const int mbase = blockIdx.x * BM;
    const int k0    = blockIdx.y * klen;
    C += (size_t)blockIdx.y * gridDim.x * BM * 128;

    // staging: A chunk 64x64 fp32 (16 floats/thread), B chunk 128x64 bf16 (4 s8v/thread)
    const int ar = t >> 2;           // 0..63
    const int ak = (t & 3) * 16;     // k offset (16 floats)
    const int br = t >> 1;           // 0..127
    const int bk = (t & 1) * 32;     // k offset (32 bf16)
    const float*          Ap = A  + (size_t)(mbase + ar) * lda + k0 + ak;
    const unsigned short* Bp = Bt + (size_t)br * ldb + k0 + bk;

    const int nchunks = klen / KC;

    float4 a_r[2][4];
    s8v    b_r[2][4];

    // ---- prologue: chunk0 -> LDS buf0; chunk1 -> regs set1 (left in flight) ----
    {
        #pragma unroll
        for (int i = 0; i < 4; ++i) a_r[0][i] = *(const float4*)(Ap + i * 4);
        #pragma unroll
        for (int i = 0; i < 4; ++i) b_r[0][i] = *(const s8v*)(Bp + i * 8);
        s8v v0, v1;
        v0[0] = (short)f2bf(a_r[0][0].x); v0[1] = (short)f2bf(a_r[0][0].y);
        v0[2] = (short)f2bf(a_r[0][0].z); v0[3] = (short)f2bf(a_r[0][0].w);
        v0[4] = (short)f2bf(a_r[0][1].x); v0[5] = (short)f2bf(a_r[0][1].y);
        v0[6] = (short)f2bf(a_r[0][1].z); v0[7] = (short)f2bf(a_r[0][1].w);
        v1[0] = (short)f2bf(a_r[0][2].x); v1[1] = (short)f2bf(a_r[0][2].y);
        v1[2] = (short)f2bf(a_r[0][2].z); v1[3] = (short)f2bf(a_r[0][2].w);
        v1[4] = (short)f2bf(a_r[0][3].x); v1[5] = (short)f2bf(a_r[0][3].y);
        v1[6] = (short)f2bf(a_r[0][3].z); v1[7] = (short)f2bf(a_r[0][3].w);
        *(s8v*)&As[0][ar * PAD + ak]     = v0;
        *(s8v*)&As[0][ar * PAD + ak + 8] = v1;
        #pragma unroll
        for (int i = 0; i < 4; ++i) *(s8v*)&Bs[0][br * PAD + bk + 8 * i] = b_r[0][i];
        if (nchunks > 1) {
            #pragma unroll
            for (int i = 0; i < 4; ++i) a_r[1][i] = *(const float4*)(Ap + KC + i * 4);
            #pragma unroll
            for (int i = 0; i < 4; ++i) b_r[1][i] = *(const s8v*)(Bp + KC + i * 8);
        }
    }
    LDS_BARRIER();

    f32x4 acc[4][2];
    #pragma unroll
    for (int rt = 0; rt < 4; ++rt)
        #pragma unroll
        for (int ct = 0; ct < 2; ++ct)
            acc[rt][ct] = (f32x4){0.f, 0.f, 0.f, 0.f};

#define GITER(p)                                                               \
    {                                                                          \
        if (c + 2 < nchunks) {  /* issue prefetch for c+2 */                   \
            const size_t o = (size_t)(c + 2) * KC;                             \
            _Pragma("unroll")                                                  \
            for (int i = 0; i < 4; ++i) a_r[p][i] = *(const float4*)(Ap + o + i * 4); \
            _Pragma("unroll")                                                  \
            for (int i = 0; i < 4; ++i) b_r[p][i] = *(const s8v*)(Bp + o + i * 8);    \
        }                                                                      \
        {   /* compute on buf p */                                             \
            const unsigned short* as = As[p];                                  \
            const unsigned short* bs = Bs[p];                                  \
            _Pragma("unroll")                                                  \
            for (int kk = 0; kk < 2; ++kk) {                                   \
                const int ko = kk * 32 + kq;                                   \
                s8v af[4], bf[2];                                              \
                _Pragma("unroll")                                              \
                for (int rt = 0; rt < 4; ++rt)                                 \
                    af[rt] = *(const s8v*)&as[(rt * 16 + l16) * PAD + ko];     \
                _Pragma("unroll")                                              \
                for (int ct = 0; ct < 2; ++ct)                                 \
                    bf[ct] = *(const s8v*)&bs[(w32 + ct * 16 + l16) * PAD + ko]; \
                _Pragma("unroll")                                              \
                for (int rt = 0; rt < 4; ++rt)                                 \
                    _Pragma("unroll")                                          \
                    for (int ct = 0; ct < 2; ++ct)                             \
                        acc[rt][ct] = __builtin_amdgcn_mfma_f32_16x16x32_bf16( \
                            af[rt], bf[ct], acc[rt][ct], 0, 0, 0);             \
            }                                                                  \
        }                                                                      \
        if (c + 1 < nchunks) {  /* convert+store chunk c+1 (loaded last iter) */ \
            const int q = (p) ^ 1;                                             \
            s8v v0, v1;                                                        \
            v0[0] = (short)f2bf(a_r[q][0].x); v0[1] = (short)f2bf(a_r[q][0].y);\
            v0[2] = (short)f2bf(a_r[q][0].z); v0[3] = (short)f2bf(a_r[q][0].w);\
            v0[4] = (short)f2bf(a_r[q][1].x); v0[5] = (short)f2bf(a_r[q][1].y);\
            v0[6] = (short)f2bf(a_r[q][1].z); v0[7] = (short)f2bf(a_r[q][1].w);\
            v1[0] = (short)f2bf(a_r[q][2].x); v1[1] = (short)f2bf(a_r[q][2].y);\
            v1[2] = (short)f2bf(a_r[q][2].z); v1[3] = (short)f2bf(a_r[q][2].w);\
            v1[4] = (short)f2bf(a_r[q][3].x); v1[5] = (short)f2bf(a_r[q][3].y);\
            v1[6] = (short)f2bf(a_r[q][3].z); v1[7] = (short)f2bf(a_r[q][3].w);\
            *(s8v*)&As[q][ar * PAD + ak]     = v0;                             \
            *(s8v*)&As[q][ar * PAD + ak + 8] = v1;                             \
            _Pragma("unroll")                                                  \
            for (int i = 0; i < 4; ++i)                                        \
                *(s8v*)&Bs[q][br * PAD + bk + 8 * i] = b_r[q][i];              \
        }                                                                      \
        LDS_BARRIER();                                                         \
    }

    int c = 0;
    while (true) {
        GITER(0)
        if (++c == nchunks) break;
        GITER(1)
        if (++c == nchunks) break;
    }
#undef GITER

    // epilogue: C/D layout col = lane&15, row = quad*4 + reg
    #pragma unroll
    for (int rt = 0; rt < 4; ++rt) {
        const int row = mbase + rt * 16 + quad * 4;
        #pragma unroll
        for (int ct = 0; ct < 2; ++ct) {
            const int col = w32 + ct * 16 + l16;
            #pragma unroll
            for (int i = 0; i < 4; ++i)
                C[(size_t)(row + i) * 128 + col] = acc[rt][ct][i];
        }
    }
}

// Transpose+convert: a = nslabs slabs of [nrows][128] fp32 (stride nrows*128).
// out[f][k] = bf16( scale(k) * sum_s a_s[k][f] ), out row stride = nrows.
// mode==1: scale(k) = sum_j dl[j][k]^2 * ft[j][k], else scale=1.
__global__ __launch_bounds__(256) void tkern(
    const float* __restrict__ a, int nslabs,
    const float* __restrict__ dl, const float* __restrict__ ft,
    unsigned short* __restrict__ out, int nrows, int mode)
{
    __shared__ __align__(16) unsigned short L[128 * PAD];
    const int t    = threadIdx.x;
    const int kb   = blockIdx.x * 64;
    const int kloc = t >> 2;
    const int fseg = (t & 3) * 32;
    const int k    = kb + kloc;
    const size_t slab = (size_t)nrows * 128;

    float s = 1.0f;
    if (mode) {
        float s0 = 0.f;
        #pragma unroll
        for (int j = 0; j < 3; ++j) {
            float d = dl[(size_t)j * nrows + k];
            s0 += d * d * ft[(size_t)j * nrows + k];
        }
        s = s0;
    }
    const float* ap = a + (size_t)k * 128 + fseg;
    #pragma unroll
    for (int i = 0; i < 8; ++i) {
        float4 v = *(const float4*)(ap + i * 4);
        for (int sl = 1; sl < nslabs; ++sl) {
            float4 u = *(const float4*)(ap + sl * slab + i * 4);
            v.x += u.x; v.y += u.y; v.z += u.z; v.w += u.w;
        }
        const int fb = fseg + i * 4;
        L[(fb + 0) * PAD + kloc] = f2bf(v.x * s);
        L[(fb + 1) * PAD + kloc] = f2bf(v.y * s);
        L[(fb + 2) * PAD + kloc] = f2bf(v.z * s);
        L[(fb + 3) * PAD + kloc] = f2bf(v.w * s);
    }
    __syncthreads();
    const int f    = t >> 1;
    const int half = (t & 1) * 32;
    unsigned short* op = out + (size_t)f * nrows + kb + half;
    #pragma unroll
    for (int i = 0; i < 4; ++i) {
        *(s8v*)(op + i * 8) = *(const s8v*)&L[f * PAD + half + i * 8];
    }
}

// out = sum of 4 partial slabs + bias
__global__ __launch_bounds__(256) void addbias_kernel(
    const float* __restrict__ p, const float* __restrict__ bias,
    float* __restrict__ out)
{
    const size_t e = ((size_t)blockIdx.x * 256 + threadIdx.x) * 4;
    const size_t slab = (size_t)8192 * 128;
    float4 r = *(const float4*)(bias + (e & 127));
    #pragma unroll
    for (int s = 0; s < 4; ++s) {
        float4 x = *(const float4*)(p + s * slab + e);
        r.x += x.x; r.y += x.y; r.z += x.z; r.w += x.w;
    }
    *(float4*)(out + e) = r;
}

extern "C" void kernel_launch(void* const* d_in, const int* in_sizes, int n_in,
                              void* d_out, int out_size, void* d_ws, size_t ws_size,
                              hipStream_t stream)
{
    const float* x  = (const float*)d_in[0];   // [8192][128]
    const float* dl = (const float*)d_in[1];   // [3][8192]
    const float* U  = (const float*)d_in[2];   // [8192][8192]
    const float* Vt = (const float*)d_in[3];   // [8192][8192]
    const float* W  = (const float*)d_in[4];   // [128][128]
    const float* ft = (const float*)d_in[5];   // [3][8192]
    const float* bs = (const float*)d_in[6];   // [128]
    float* out = (float*)d_out;

    const int N = 8192, F = 128;
    const int SPLITK = 4;
    char* ws = (char*)d_ws;
    unsigned short* Wt  = (unsigned short*)(ws);                           // 32KB (64KB reserved)
    unsigned short* xwt = (unsigned short*)(ws + (64 << 10));              // 2MB  bf16 [128][8192]
    unsigned short* yt  = (unsigned short*)(ws + (64 << 10) + (2 << 20));  // 2MB  bf16 [128][8192]
    float* bufA = (float*)(ws + (64 << 10) + (4 << 20));                   // 16MB: xw fp32 / out partials x4
    float* bufB = (float*)(ws + (64 << 10) + (20 << 20));                  // 16MB: y partials x4

    // T0: Wt[f][c] = bf16(W[c][f])
    tkern<<<dim3(F / 64), 256, 0, stream>>>(W, 1, nullptr, nullptr, Wt, F, 0);
    // G1: xw = x @ W
    gemm_kernel<<<dim3(N / BM, 1), 256, 0, stream>>>(x, F, Wt, F, bufA, F);
    // T1: xwt[f][n] = bf16(xw[n][f])
    tkern<<<dim3(N / 64), 256, 0, stream>>>(bufA, 1, nullptr, nullptr, xwt, N, 0);
    // G2: y partials = Vt @ xw  (split-K 4)
    gemm_kernel<<<dim3(N / BM, SPLITK), 256, 0, stream>>>(Vt, N, xwt, N, bufB, N / SPLITK);
    // T2: yt[f][k] = bf16( scale(k) * sum_s y_s[k][f] )
    tkern<<<dim3(N / 64), 256, 0, stream>>>(bufB, SPLITK, dl, ft, yt, N, 1);
    // G3: out partials = U @ y  (split-K 4)
    gemm_kernel<<<dim3(N / BM, SPLITK), 256, 0, stream>>>(U, N, yt, N, bufA, N / SPLITK);
    // T3: out = sum partials + bias
    addbias_kernel<<<dim3((N * F) / (256 * 4)), 256, 0, stream>>>(bufA, bs, out);
}